// Round 1
// baseline (567.776 us; speedup 1.0000x reference)
//
#include <hip/hip_runtime.h>

// FullyAdjacent rewiring: output is [2, G*N*N] int32, flattened.
//   rows half: out[j]        = (j % N^2) / N      (j in [0, half))
//   cols half: out[half + i] = i % N              (i in [0, half))
// N = in_sizes[2] (batch length), half = out_size/2 (G baked in by harness).
//
// Round 3: grid-stride rewrite. Previous version launched 131,072 workgroups
// with ONE dwordx4 store per thread (1 KB/wave) -> per-wg launch/teardown
// dominated, ~3.3 TB/s effective. Now 2048 blocks x 256 threads (8 blocks/CU
// across 256 CUs), each thread stores 64 B (4 x dwordx4) per loop iteration,
// ~16 iterations/thread -- the same shape as rocclr's fillBufferAligned,
// which sustains 6.3 TB/s on this chip.
// Plain (cached) stores: nontemporal measured 1.07 TB/s in round 2 — keep L2.

typedef int v4i __attribute__((ext_vector_type(4)));

__global__ __launch_bounds__(256) void fa_pow2_kernel(
    int* __restrict__ out,
    unsigned n16,       // number of 16-int32 groups = n/16
    unsigned half,      // n/2 in int32 elements, multiple of 16
    int shiftN,         // log2(N)
    int maskN)          // N-1
{
    unsigned tid    = blockIdx.x * blockDim.x + threadIdx.x;
    unsigned stride = gridDim.x * blockDim.x;
    for (unsigned g = tid; g < n16; g += stride) {
        unsigned j = g << 4;            // int32 index of this thread's 16-group
        v4i* p = (v4i*)(out + j);
        if (j < half) {
            // rows: (j % N^2)/N == (j >> shiftN) & maskN for pow2 N.
            // Constant across the 16-group since 16 | N.
            int r = (int)((j >> shiftN) & (unsigned)maskN);
            v4i v = (v4i){r, r, r, r};
            p[0] = v; p[1] = v; p[2] = v; p[3] = v;
        } else {
            // cols: (j - half) % N; no wrap inside the 16-group since 16 | N
            // and half % 16 == 0.
            int c = (int)((j - half) & (unsigned)maskN);
            p[0] = (v4i){c,      c + 1,  c + 2,  c + 3};
            p[1] = (v4i){c + 4,  c + 5,  c + 6,  c + 7};
            p[2] = (v4i){c + 8,  c + 9,  c + 10, c + 11};
            p[3] = (v4i){c + 12, c + 13, c + 14, c + 15};
        }
    }
}

// Fallback for non-pow2 N or unaligned sizes (not expected for this problem).
__global__ __launch_bounds__(256) void fa_generic_kernel(
    int* __restrict__ out, long long n, long long half, long long N)
{
    long long tid    = (long long)blockIdx.x * blockDim.x + threadIdx.x;
    long long stride = (long long)gridDim.x * blockDim.x;
    long long NN = N * N;
    for (long long j = tid; j < n; j += stride) {
        int val;
        if (j < half) val = (int)((j % NN) / N);
        else          val = (int)((j - half) % N);
        out[j] = val;
    }
}

extern "C" void kernel_launch(void* const* d_in, const int* in_sizes, int n_in,
                              void* d_out, int out_size, void* d_ws, size_t ws_size,
                              hipStream_t stream) {
    (void)d_in; (void)d_ws; (void)ws_size;
    int* out = (int*)d_out;
    long long n = (long long)out_size;
    long long half = n / 2;
    long long N = (n_in >= 3) ? (long long)in_sizes[2] : 4096;  // batch length

    bool pow2 = (N > 0) && ((N & (N - 1)) == 0);
    bool aligned = (n % 16 == 0) && (half % 16 == 0) && (N % 16 == 0);

    if (pow2 && aligned) {
        int shiftN = 0;
        while ((1LL << shiftN) < N) ++shiftN;
        int maskN = (int)(N - 1);
        long long n16 = n >> 4;
        int block = 256;
        long long grid = (n16 + block - 1) / block;
        if (grid > 2048) grid = 2048;   // 8 blocks/CU x 256 CUs; grid-stride
        fa_pow2_kernel<<<(dim3)(unsigned)grid, block, 0, stream>>>(
            out, (unsigned)n16, (unsigned)half, shiftN, maskN);
    } else {
        int block = 256;
        long long grid = (n + block - 1) / block;
        if (grid > 2048) grid = 2048;
        fa_generic_kernel<<<(dim3)(unsigned)grid, block, 0, stream>>>(
            out, n, half, N);
    }
}

// Round 2
// 532.395 us; speedup vs baseline: 1.0665x; 1.0665x over previous
//
#include <hip/hip_runtime.h>

// FullyAdjacent rewiring: output is [2, G*N*N] int32, flattened.
//   rows half: out[j]        = (j % N^2) / N      (j in [0, half))
//   cols half: out[half + i] = i % N              (i in [0, half))
// N = in_sizes[2] (batch length), half = out_size/2 (G baked in by harness).
//
// Round 4: grid-stride WITH round-0's coalescing restored.
// Round-1 post-mortem: giving each thread 64 contiguous bytes made every
// individual global_store_dwordx4 a 64-lane scatter at stride 64 B (partial
// 64B-sector writes, merged across 4 instructions) -> regressed to ~227 us.
// Round-0 mapping (lane i -> base + i*16) makes every store instruction a
// contiguous 1 KB wave write. Keep that mapping exactly; add work-per-thread
// by spacing a thread's successive stores a full GRID apart, so each of the
// 4 unrolled stores per iteration is still a perfect 1 KB wave write.
// Plain (cached) stores: nontemporal measured 1.07 TB/s previously — keep L2.

typedef int v4i __attribute__((ext_vector_type(4)));

__device__ __forceinline__ v4i fa_val(unsigned j, unsigned half,
                                      int shiftN, int maskN) {
    if (j < half) {
        // rows: (j % N^2)/N == (j >> shiftN) & maskN for pow2 N.
        // Constant across the 4-group since 4 | N.
        int r = (int)((j >> shiftN) & (unsigned)maskN);
        return (v4i){r, r, r, r};
    } else {
        // cols: (j - half) % N; no wrap inside the 4-group since 4 | N.
        int c = (int)((j - half) & (unsigned)maskN);
        return (v4i){c, c + 1, c + 2, c + 3};
    }
}

__global__ __launch_bounds__(256) void fa_pow2_kernel(
    int* __restrict__ out,
    unsigned n4,        // number of 4-int32 groups = n/4
    unsigned half,      // n/2 in int32 elements, multiple of 4
    int shiftN,         // log2(N)
    int maskN)          // N-1
{
    unsigned tid = blockIdx.x * blockDim.x + threadIdx.x;
    unsigned T   = gridDim.x * blockDim.x;   // total threads
    unsigned g   = tid;
    // Main loop: 4 stores per iteration, each wave-contiguous (1 KB/instr).
    for (; g + 3u * T < n4; g += 4u * T) {
        #pragma unroll
        for (unsigned u = 0; u < 4; ++u) {
            unsigned j = (g + u * T) << 2;
            *(v4i*)(out + j) = fa_val(j, half, shiftN, maskN);
        }
    }
    // Tail (empty when T*4 divides n4, which holds for this problem).
    for (; g < n4; g += T) {
        unsigned j = g << 2;
        *(v4i*)(out + j) = fa_val(j, half, shiftN, maskN);
    }
}

// Fallback for non-pow2 N or unaligned sizes (not expected for this problem).
__global__ __launch_bounds__(256) void fa_generic_kernel(
    int* __restrict__ out, long long n, long long half, long long N)
{
    long long tid    = (long long)blockIdx.x * blockDim.x + threadIdx.x;
    long long stride = (long long)gridDim.x * blockDim.x;
    long long NN = N * N;
    for (long long j = tid; j < n; j += stride) {
        int val;
        if (j < half) val = (int)((j % NN) / N);
        else          val = (int)((j - half) % N);
        out[j] = val;
    }
}

extern "C" void kernel_launch(void* const* d_in, const int* in_sizes, int n_in,
                              void* d_out, int out_size, void* d_ws, size_t ws_size,
                              hipStream_t stream) {
    (void)d_in; (void)d_ws; (void)ws_size;
    int* out = (int*)d_out;
    long long n = (long long)out_size;
    long long half = n / 2;
    long long N = (n_in >= 3) ? (long long)in_sizes[2] : 4096;  // batch length

    bool pow2 = (N > 0) && ((N & (N - 1)) == 0);
    bool aligned = (n % 4 == 0) && (half % 4 == 0) && (N % 4 == 0);

    if (pow2 && aligned) {
        int shiftN = 0;
        while ((1LL << shiftN) < N) ++shiftN;
        int maskN = (int)(N - 1);
        long long n4 = n >> 2;
        int block = 256;
        long long grid = (n4 + block - 1) / block;
        if (grid > 2048) grid = 2048;   // 8 blocks/CU x 256 CUs; grid-stride
        fa_pow2_kernel<<<(dim3)(unsigned)grid, block, 0, stream>>>(
            out, (unsigned)n4, (unsigned)half, shiftN, maskN);
    } else {
        int block = 256;
        long long grid = (n + block - 1) / block;
        if (grid > 2048) grid = 2048;
        fa_generic_kernel<<<(dim3)(unsigned)grid, block, 0, stream>>>(
            out, n, half, N);
    }
}

// Round 3
// 514.815 us; speedup vs baseline: 1.1029x; 1.0341x over previous
//
#include <hip/hip_runtime.h>

// FullyAdjacent rewiring: output is [2, G*N*N] int32, flattened.
//   rows half: out[j]        = (j % N^2) / N      (j in [0, half))
//   cols half: out[half + i] = i % N              (i in [0, half))
//
// Round 5: chunked sequential streaming, modeled on rocclr fillBufferAligned's
// counter signature (6.3 TB/s at ~10% occupancy ~= 200 blocks).
// History:
//   r0: 131K one-shot wgs, 1 store/thread           -> ~161 us (3.3 TB/s)
//   r1: 2048 blocks, 64B/thread contiguous          -> ~227 us (per-instr scatter)
//   r2: 2048 blocks, 4 slots 8MB apart per thread   -> ~190 us (32K scattered streams)
// Lesson: pure-store kernels are limited by write-stream LOCALITY, not
// parallelism. This version: 256 blocks (1/CU), each block streams ONE
// contiguous 2MB chunk front-to-back; wave w writes slot (step*4+w), so every
// store instruction is a contiguous 1KB wave write and the block's address
// stream is strictly sequential. Plain cached stores (nt measured 1.07 TB/s).

typedef int v4i __attribute__((ext_vector_type(4)));

__global__ __launch_bounds__(256) void fa_chunk_kernel(
    int* __restrict__ out,
    unsigned chunk,      // elements per block; multiple of 4096
    unsigned half,       // elements in rows half; chunk divides half
    int shiftN,          // log2(N)
    int maskN)           // N-1
{
    unsigned base = blockIdx.x * chunk;
    unsigned end  = base + chunk;
    unsigned wave = threadIdx.x >> 6;        // 0..3
    unsigned lane = threadIdx.x & 63u;
    // element index of this thread's first 4-int group
    unsigned e = base + wave * 256u + lane * 4u;

    if (base < half) {
        // rows half (block-uniform: chunk divides half).
        // r = (j >> shiftN) & maskN, constant within a 256-elem slot (N>=256).
        for (; e < end; e += 4096u) {
            #pragma unroll
            for (unsigned u = 0; u < 4; ++u) {
                unsigned j = e + u * 1024u;
                int r = (int)((j >> shiftN) & (unsigned)maskN);
                *(v4i*)(out + j) = (v4i){r, r, r, r};
            }
        }
    } else {
        // cols half: c = (j - half) & maskN; no wrap inside a lane's 4-group
        // since 4 | N and half, slots are 4-aligned.
        for (; e < end; e += 4096u) {
            #pragma unroll
            for (unsigned u = 0; u < 4; ++u) {
                unsigned j = e + u * 1024u;
                int c = (int)((j - half) & (unsigned)maskN);
                *(v4i*)(out + j) = (v4i){c, c + 1, c + 2, c + 3};
            }
        }
    }
}

// Fallback for non-pow2 N or unaligned sizes (not expected for this problem).
__global__ __launch_bounds__(256) void fa_generic_kernel(
    int* __restrict__ out, long long n, long long half, long long N)
{
    long long tid    = (long long)blockIdx.x * blockDim.x + threadIdx.x;
    long long stride = (long long)gridDim.x * blockDim.x;
    long long NN = N * N;
    for (long long j = tid; j < n; j += stride) {
        int val;
        if (j < half) val = (int)((j % NN) / N);
        else          val = (int)((j - half) % N);
        out[j] = val;
    }
}

extern "C" void kernel_launch(void* const* d_in, const int* in_sizes, int n_in,
                              void* d_out, int out_size, void* d_ws, size_t ws_size,
                              hipStream_t stream) {
    (void)d_in; (void)d_ws; (void)ws_size;
    int* out = (int*)d_out;
    long long n = (long long)out_size;     // total int32 elements
    long long half = n / 2;
    long long N = (n_in >= 3) ? (long long)in_sizes[2] : 4096;  // batch length

    const long long GRID = 256;            // 1 block/CU, 4 waves/CU
    bool pow2 = (N >= 256) && ((N & (N - 1)) == 0);
    // need: chunk = n/GRID multiple of 4096 elems (16KB), half % chunk == 0
    bool divisible = (n % (GRID * 4096) == 0);

    if (pow2 && divisible) {
        long long chunk = n / GRID;        // elements per block
        // half = n/2, chunk = n/256 -> half/chunk = 128 exactly
        int shiftN = 0;
        while ((1LL << shiftN) < N) ++shiftN;
        int maskN = (int)(N - 1);
        fa_chunk_kernel<<<(dim3)(unsigned)GRID, 256, 0, stream>>>(
            out, (unsigned)chunk, (unsigned)half, shiftN, maskN);
    } else {
        int block = 256;
        long long grid = (n + block - 1) / block;
        if (grid > 2048) grid = 2048;
        fa_generic_kernel<<<(dim3)(unsigned)grid, block, 0, stream>>>(
            out, n, half, N);
    }
}